// Round 5
// baseline (350.901 us; speedup 1.0000x reference)
//
#include <hip/hip_runtime.h>

typedef short short8 __attribute__((ext_vector_type(8)));
typedef float floatx4 __attribute__((ext_vector_type(4)));

#define D16 16
#define KC 512
// tokens: B(8) * heads(8) * HW(4096)
#define NTOK (8 * 8 * 4096)

// workspace layout:
//   [0, 512*17*4)            : M   = K x 17 fp32  (O_tV sums | count)
//   [36864, 36864 + NTOK*2)  : idx = ushort per token

__device__ __forceinline__ unsigned short rne_bf16(float x) {
    unsigned u = __float_as_uint(x);
    return (unsigned short)((u + 0x7fffu + ((u >> 16) & 1u)) >> 16);
}
__device__ __forceinline__ float bf16_to_f32(unsigned short h) {
    return __uint_as_float(((unsigned)h) << 16);
}

// ---------------- kernel 1: nearest-code assignment ----------------
// MFMA split-bf16 scores select top-2 candidates per token; exact fp32
// rescore (round-1's formula dist = fmaf(-2, k.c, |c|^2)) decides.
extern "C" __global__ __launch_bounds__(256)
void vq_assign(const float* __restrict__ qkv, const float* __restrict__ cb,
               unsigned short* __restrict__ idx)
{
    __shared__ alignas(16) unsigned short s_cbh[KC * 16];  // 16 KB
    __shared__ alignas(16) unsigned short s_cbr[KC * 16];  // 16 KB
    __shared__ float s_cn[KC];                             // 2 KB  |c|^2 (full)
    __shared__ float s_kf[4][16][17];                      // 4.25 KB per-wave fp32 k tiles
    int tid = threadIdx.x;
    for (int i = tid; i < KC * 16; i += 256) {
        float x = cb[i];
        unsigned short h = rne_bf16(x);
        s_cbh[i] = h;
        s_cbr[i] = rne_bf16(x - bf16_to_f32(h));
    }
    for (int j = tid; j < KC; j += 256) {
        float s = 0.f;
#pragma unroll
        for (int d = 0; d < D16; ++d) { float c = cb[j * D16 + d]; s = fmaf(c, c, s); }
        s_cn[j] = s;
    }
    __syncthreads();

    int lane = tid & 63;
    int col = lane & 15;
    int lg = (lane >> 4) & 1;
    int wv = tid >> 6;
    // block covers 4 waves * 4 tiles * 16 tokens = 256 tokens
    int tile0 = (blockIdx.x * 4 + wv) * 4;

    for (int t = 0; t < 4; ++t) {
        int tok0 = (tile0 + t) * 16;
        int bh = tok0 >> 12;
        const float* kbase = qkv + (size_t)bh * (48 * 4096) + 16 * 4096 + (tok0 & 4095);

        short8 ah = (short8)0, ar = (short8)0;
        if (lane < 32) {
            const float* p = kbase + (size_t)((lane >> 4) * 8) * 4096 + (lane & 15);
#pragma unroll
            for (int i = 0; i < 8; ++i) {
                float x = p[(size_t)i * 4096];
                unsigned short h = rne_bf16(x);
                ah[i] = (short)h;
                ar[i] = (short)rne_bf16(x - bf16_to_f32(h));
                s_kf[wv][lane & 15][(lane >> 4) * 8 + i] = x;  // exact fp32 copy for rescore
            }
        }
        __syncthreads();

        float b1[4], b2[4]; int i1[4], i2[4];
#pragma unroll
        for (int r = 0; r < 4; ++r) { b1[r] = -3.4e38f; b2[r] = -3.4e38f; i1[r] = 0; i2[r] = 0; }

        for (int c = 0; c < 32; ++c) {
            int code = c * 16 + col;
            short8 bh8 = *(const short8*)(&s_cbh[code * 16 + lg * 8]);
            short8 br8 = *(const short8*)(&s_cbr[code * 16 + lg * 8]);
            float cn2 = -0.5f * s_cn[code];
            floatx4 acc = { cn2, cn2, cn2, cn2 };
            acc = __builtin_amdgcn_mfma_f32_16x16x32_bf16(ah, bh8, acc, 0, 0, 0);
            acc = __builtin_amdgcn_mfma_f32_16x16x32_bf16(ar, bh8, acc, 0, 0, 0);
            acc = __builtin_amdgcn_mfma_f32_16x16x32_bf16(ah, br8, acc, 0, 0, 0);
#pragma unroll
            for (int r = 0; r < 4; ++r) {
                float s = acc[r];
                if (s > b1[r]) { b2[r] = b1[r]; i2[r] = i1[r]; b1[r] = s; i1[r] = code; }
                else if (s > b2[r]) { b2[r] = s; i2[r] = code; }
            }
        }
        // merge top-2 across the 16 code-columns (lanes sharing a row group)
#pragma unroll
        for (int m = 1; m < 16; m <<= 1) {
#pragma unroll
            for (int r = 0; r < 4; ++r) {
                float ob1 = __shfl_xor(b1[r], m, 64); int oi1 = __shfl_xor(i1[r], m, 64);
                float ob2 = __shfl_xor(b2[r], m, 64); int oi2 = __shfl_xor(i2[r], m, 64);
                if (ob1 > b1[r]) {
                    if (b1[r] > ob2) { b2[r] = b1[r]; i2[r] = i1[r]; }
                    else             { b2[r] = ob2;   i2[r] = oi2;   }
                    b1[r] = ob1; i1[r] = oi1;
                } else if (ob1 > b2[r]) {
                    b2[r] = ob1; i2[r] = oi1;
                }
            }
        }
        // exact fp32 rescore of the 2 candidates; lanes with col<4 own row col
        if (col < 4) {
            int c1 = 0, c2 = 0;
#pragma unroll
            for (int r = 0; r < 4; ++r) {
                if (col == r) { c1 = i1[r]; c2 = i2[r]; }
            }
            int tokrow = (lane >> 4) * 4 + col;
            const float* kf = &s_kf[wv][tokrow][0];
            const float* cb1 = cb + c1 * D16;
            const float* cb2 = cb + c2 * D16;
            float dot1 = 0.f, dot2 = 0.f;
#pragma unroll
            for (int d = 0; d < D16; ++d) {
                float kx = kf[d];
                dot1 = fmaf(kx, cb1[d], dot1);
                dot2 = fmaf(kx, cb2[d], dot2);
            }
            float d1 = fmaf(-2.f, dot1, s_cn[c1]);
            float d2 = fmaf(-2.f, dot2, s_cn[c2]);
            int jw = (d2 < d1 || (d2 == d1 && c2 < c1)) ? c2 : c1;
            idx[tok0 + tokrow] = (unsigned short)jw;
        }
        __syncthreads();
    }
}

// ---------------- kernel 2: segment sum of v + counts ----------------
extern "C" __global__ __launch_bounds__(256)
void vq_segsum(const float* __restrict__ qkv, const unsigned short* __restrict__ idx,
               float* __restrict__ M)
{
    __shared__ float s_acc[KC * 17];   // 34.8 KB
    for (int i = threadIdx.x; i < KC * 17; i += 256) s_acc[i] = 0.f;
    __syncthreads();

    for (int n = blockIdx.x * 256 + threadIdx.x; n < NTOK; n += gridDim.x * 256) {
        int bh = n >> 12, hw = n & 4095;
        const float* bv = qkv + (size_t)bh * (48 * 4096) + hw + 32 * 4096;
        int bj = idx[n];
#pragma unroll
        for (int d = 0; d < D16; ++d)
            atomicAdd(&s_acc[bj * 17 + d], bv[d * 4096]);
        atomicAdd(&s_acc[bj * 17 + 16], 1.0f);
    }
    __syncthreads();
    for (int i = threadIdx.x; i < KC * 17; i += 256)
        atomicAdd(&M[i], s_acc[i]);
}

// ---------------- kernel 3: softmax-weighted gather (MFMA) ----------------
extern "C" __global__ __launch_bounds__(256)
void vq_attend(const float* __restrict__ qkv, const float* __restrict__ cb,
               const float* __restrict__ M, float* __restrict__ out)
{
    __shared__ alignas(16) unsigned short s_cbh[KC * 16];    // 16 KB
    __shared__ alignas(16) unsigned short s_cbr[KC * 16];    // 16 KB
    __shared__ alignas(16) unsigned short s_mt[16 * 520];    // 16.25 KB  M^T bf16, padded
    __shared__ float s_cnt[KC];                              // 2 KB
    __shared__ alignas(16) unsigned short s_wh[4][16 * 40];  // 5 KB  per-wave w hi tiles
    __shared__ alignas(16) unsigned short s_wr[4][16 * 40];  // 5 KB  per-wave w residual tiles

    int tid = threadIdx.x;
    for (int i = tid; i < KC * 16; i += 256) {
        float x = cb[i];
        unsigned short h = rne_bf16(x);
        s_cbh[i] = h;
        s_cbr[i] = rne_bf16(x - bf16_to_f32(h));
    }
    for (int i = tid; i < KC * 17; i += 256) {
        int j = i / 17, d = i - j * 17;
        float x = M[i];
        if (d == 16) s_cnt[j] = x;
        else s_mt[d * 520 + j] = rne_bf16(x);
    }
    __syncthreads();

    int lane = tid & 63;
    int col = lane & 15;
    int lg = (lane >> 4) & 1;
    int wv_id = tid >> 6;
    unsigned short* wlh = &s_wh[wv_id][0];
    unsigned short* wlr = &s_wr[wv_id][0];
    // block covers 4 waves * 4 tiles * 16 tokens = 256 tokens
    int tile0 = (blockIdx.x * 4 + wv_id) * 4;

    for (int t = 0; t < 4; ++t) {
        int tok0 = (tile0 + t) * 16;
        int bh = tok0 >> 12;
        const float* qbase = qkv + (size_t)bh * (48 * 4096) + (tok0 & 4095);

        short8 qh = (short8)0, qr = (short8)0;
        if (lane < 32) {
            const float* p = qbase + (size_t)((lane >> 4) * 8) * 4096 + (lane & 15);
#pragma unroll
            for (int i = 0; i < 8; ++i) {
                float x = p[(size_t)i * 4096];
                unsigned short h = rne_bf16(x);
                qh[i] = (short)h;
                qr[i] = (short)rne_bf16(x - bf16_to_f32(h));
            }
        }

        floatx4 oacc = {0.f, 0.f, 0.f, 0.f};
        float den[4] = {0.f, 0.f, 0.f, 0.f};

        for (int c = 0; c < 32; ++c) {
            int code = c * 16 + col;
            short8 bh8 = *(const short8*)(&s_cbh[code * 16 + lg * 8]);
            short8 br8 = *(const short8*)(&s_cbr[code * 16 + lg * 8]);
            floatx4 s = {0.f, 0.f, 0.f, 0.f};
            s = __builtin_amdgcn_mfma_f32_16x16x32_bf16(qh, bh8, s, 0, 0, 0);
            s = __builtin_amdgcn_mfma_f32_16x16x32_bf16(qr, bh8, s, 0, 0, 0);
            s = __builtin_amdgcn_mfma_f32_16x16x32_bf16(qh, br8, s, 0, 0, 0);

            float cnt = s_cnt[code];
            int cl = (c & 1) * 16 + col;
#pragma unroll
            for (int r = 0; r < 4; ++r) {
                float wv = __expf(s[r]);
                unsigned short wbh = rne_bf16(wv);
                unsigned short wbr = rne_bf16(wv - bf16_to_f32(wbh));
                den[r] = fmaf(wv, cnt, den[r]);   // exact fp32 w, matches split-w numerator
                int widx = ((lane >> 4) * 4 + r) * 40 + cl;
                wlh[widx] = wbh;
                wlr[widx] = wbr;
            }
            if (c & 1) {
                // PV over the 32 codes just materialized: w = wh + wr (split bf16)
                int aoff = (lane & 15) * 40 + (lane >> 4) * 8;
                short8 wah = *(const short8*)(&wlh[aoff]);
                short8 war = *(const short8*)(&wlr[aoff]);
                short8 mb = *(const short8*)(&s_mt[(lane & 15) * 520 + (c - 1) * 16 + (lane >> 4) * 8]);
                oacc = __builtin_amdgcn_mfma_f32_16x16x32_bf16(wah, mb, oacc, 0, 0, 0);
                oacc = __builtin_amdgcn_mfma_f32_16x16x32_bf16(war, mb, oacc, 0, 0, 0);
            }
        }
        // denominator: sum across the 16 code-columns per row group
#pragma unroll
        for (int m = 1; m < 16; m <<= 1) {
#pragma unroll
            for (int r = 0; r < 4; ++r) den[r] += __shfl_xor(den[r], m, 64);
        }
#pragma unroll
        for (int r = 0; r < 4; ++r) {
            int row = (lane >> 4) * 4 + r;
            float o = oacc[r] / (den[r] + 1e-15f);
            out[(size_t)(tok0 + row) * D16 + col] = o;
        }
    }
}

extern "C" void kernel_launch(void* const* d_in, const int* in_sizes, int n_in,
                              void* d_out, int out_size, void* d_ws, size_t ws_size,
                              hipStream_t stream) {
    const float* qkv = (const float*)d_in[0];   // (8, 384, 64, 64) fp32
    const float* cb  = (const float*)d_in[1];   // (512, 16) fp32
    float* out = (float*)d_out;                 // (8, 128, 64, 64) fp32

    float* M = (float*)d_ws;                                   // K x 17 fp32
    unsigned short* idx = (unsigned short*)((char*)d_ws + 36864);

    hipMemsetAsync(d_ws, 0, KC * 17 * sizeof(float), stream);

    // 256 tokens per block -> NTOK/256 = 1024 blocks
    vq_assign<<<NTOK / 256, 256, 0, stream>>>(qkv, cb, idx);
    vq_segsum<<<256, 256, 0, stream>>>(qkv, idx, M);
    vq_attend<<<NTOK / 256, 256, 0, stream>>>(qkv, cb, M, out);
}

// Round 6
// 280.702 us; speedup vs baseline: 1.2501x; 1.2501x over previous
//
#include <hip/hip_runtime.h>

typedef short short8 __attribute__((ext_vector_type(8)));
typedef float floatx4 __attribute__((ext_vector_type(4)));

#define D16 16
#define KC 512
// tokens: B(8) * heads(8) * HW(4096)
#define NTOK (8 * 8 * 4096)

// workspace layout:
//   [0, 512*17*4)            : M   = K x 17 fp32  (O_tV sums | count)
//   [36864, 36864 + NTOK*2)  : idx = ushort per token

__device__ __forceinline__ unsigned short rne_bf16(float x) {
    unsigned u = __float_as_uint(x);
    return (unsigned short)((u + 0x7fffu + ((u >> 16) & 1u)) >> 16);
}
__device__ __forceinline__ float bf16_to_f32(unsigned short h) {
    return __uint_as_float(((unsigned)h) << 16);
}

// ---------------- kernel 1: nearest-code assignment ----------------
// MFMA split-bf16 scores ([kh|kr] x [ch|ch] + [kh|kr] x [cr|0], 2 MFMA)
// select top-2 candidates per token via packed-float max (code index in the
// low 9 mantissa bits); exact fp32 rescore decides. No block barriers in the
// tile loop (s_kf is per-wave; same-wave LDS ordering via waitcnt).
extern "C" __global__ __launch_bounds__(256)
void vq_assign(const float* __restrict__ qkv, const float* __restrict__ cb,
               unsigned short* __restrict__ idx)
{
    __shared__ alignas(16) unsigned short s_cbh[KC * 16];  // 16 KB
    __shared__ alignas(16) unsigned short s_cbr[KC * 16];  // 16 KB
    __shared__ float s_cn[KC];                             // 2 KB  |c|^2 (full)
    __shared__ float s_kf[4][16][17];                      // 4.25 KB per-wave fp32 k tiles
    int tid = threadIdx.x;
    for (int i = tid; i < KC * 16; i += 256) {
        float x = cb[i];
        unsigned short h = rne_bf16(x);
        s_cbh[i] = h;
        s_cbr[i] = rne_bf16(x - bf16_to_f32(h));
    }
    for (int j = tid; j < KC; j += 256) {
        float s = 0.f;
#pragma unroll
        for (int d = 0; d < D16; ++d) { float c = cb[j * D16 + d]; s = fmaf(c, c, s); }
        s_cn[j] = s;
    }
    __syncthreads();

    int lane = tid & 63;
    int col = lane & 15;
    int half8 = ((lane >> 4) & 1) * 8;   // k-dim sub-block this lane covers
    bool hiHalf = lane < 32;
    int wv = tid >> 6;
    // block covers 4 waves * 4 tiles * 16 tokens = 256 tokens
    int tile0 = (blockIdx.x * 4 + wv) * 4;

    for (int t = 0; t < 4; ++t) {
        int tok0 = (tile0 + t) * 16;
        int bh = tok0 >> 12;
        const float* kbase = qkv + (size_t)bh * (48 * 4096) + 16 * 4096 + (tok0 & 4095);

        // A = [kh | kr]: lanes 0-31 carry hi(k), lanes 32-63 carry residual(k)
        short8 a8;
        {
            const float* p = kbase + (size_t)half8 * 4096 + col;
#pragma unroll
            for (int i = 0; i < 8; ++i) {
                float x = p[(size_t)i * 4096];
                unsigned short h = rne_bf16(x);
                a8[i] = hiHalf ? (short)h : (short)rne_bf16(x - bf16_to_f32(h));
                if (hiHalf) s_kf[wv][col][half8 + i] = x;  // exact fp32 copy for rescore
            }
        }
        __builtin_amdgcn_wave_barrier();

        // packed top-2 per row: score with code index stuffed in low 9 bits
        float p1[4], p2[4];
#pragma unroll
        for (int r = 0; r < 4; ++r) { p1[r] = -3.4e38f; p2[r] = -3.4e38f; }

        for (int c = 0; c < 32; ++c) {
            int code = c * 16 + col;
            short8 b1 = *(const short8*)(&s_cbh[code * 16 + half8]);  // [ch|ch]
            short8 b2 = (short8)0;
            if (hiHalf) b2 = *(const short8*)(&s_cbr[code * 16 + half8]);  // [cr|0]
            float cn2 = -0.5f * s_cn[code];
            floatx4 acc = { cn2, cn2, cn2, cn2 };
            acc = __builtin_amdgcn_mfma_f32_16x16x32_bf16(a8, b1, acc, 0, 0, 0);
            acc = __builtin_amdgcn_mfma_f32_16x16x32_bf16(a8, b2, acc, 0, 0, 0);
#pragma unroll
            for (int r = 0; r < 4; ++r) {
                unsigned sb = (__float_as_uint(acc[r]) & 0xFFFFFE00u) | (unsigned)code;
                float sp = __uint_as_float(sb);
                float old1 = p1[r];
                p1[r] = fmaxf(old1, sp);
                p2[r] = fmaxf(p2[r], fminf(old1, sp));
            }
        }
        // merge top-2 across the 16 code-columns (lanes sharing a row group)
#pragma unroll
        for (int m = 1; m < 16; m <<= 1) {
#pragma unroll
            for (int r = 0; r < 4; ++r) {
                float o1 = __shfl_xor(p1[r], m, 64);
                float o2 = __shfl_xor(p2[r], m, 64);
                float n1 = fmaxf(p1[r], o1);
                float n2 = fmaxf(fminf(p1[r], o1), fmaxf(p2[r], o2));
                p1[r] = n1; p2[r] = n2;
            }
        }
        // exact fp32 rescore of the 2 candidates; lanes with col<4 own row col
        if (col < 4) {
            int c1 = 0, c2 = 0;
#pragma unroll
            for (int r = 0; r < 4; ++r) {
                if (col == r) {
                    c1 = (int)(__float_as_uint(p1[r]) & 511u);
                    c2 = (int)(__float_as_uint(p2[r]) & 511u);
                }
            }
            int tokrow = (lane >> 4) * 4 + col;
            const float* kf = &s_kf[wv][tokrow][0];
            const float* cb1 = cb + c1 * D16;
            const float* cb2 = cb + c2 * D16;
            float dot1 = 0.f, dot2 = 0.f;
#pragma unroll
            for (int d = 0; d < D16; ++d) {
                float kx = kf[d];
                dot1 = fmaf(kx, cb1[d], dot1);
                dot2 = fmaf(kx, cb2[d], dot2);
            }
            float d1 = fmaf(-2.f, dot1, s_cn[c1]);
            float d2 = fmaf(-2.f, dot2, s_cn[c2]);
            int jw = (d2 < d1 || (d2 == d1 && c2 < c1)) ? c2 : c1;
            idx[tok0 + tokrow] = (unsigned short)jw;
        }
        __builtin_amdgcn_wave_barrier();
    }
}

// ---------------- kernel 2: segment sum of v + counts ----------------
extern "C" __global__ __launch_bounds__(256)
void vq_segsum(const float* __restrict__ qkv, const unsigned short* __restrict__ idx,
               float* __restrict__ M)
{
    __shared__ float s_acc[KC * 17];   // 34.8 KB
    for (int i = threadIdx.x; i < KC * 17; i += 256) s_acc[i] = 0.f;
    __syncthreads();

    for (int n = blockIdx.x * 256 + threadIdx.x; n < NTOK; n += gridDim.x * 256) {
        int bh = n >> 12, hw = n & 4095;
        const float* bv = qkv + (size_t)bh * (48 * 4096) + hw + 32 * 4096;
        int bj = idx[n];
#pragma unroll
        for (int d = 0; d < D16; ++d)
            atomicAdd(&s_acc[bj * 17 + d], bv[d * 4096]);
        atomicAdd(&s_acc[bj * 17 + 16], 1.0f);
    }
    __syncthreads();
    for (int i = threadIdx.x; i < KC * 17; i += 256)
        atomicAdd(&M[i], s_acc[i]);
}

// ---------------- kernel 3: softmax-weighted gather (MFMA) ----------------
extern "C" __global__ __launch_bounds__(256)
void vq_attend(const float* __restrict__ qkv, const float* __restrict__ cb,
               const float* __restrict__ M, float* __restrict__ out)
{
    __shared__ alignas(16) unsigned short s_cbh[KC * 16];    // 16 KB
    __shared__ alignas(16) unsigned short s_cbr[KC * 16];    // 16 KB
    __shared__ alignas(16) unsigned short s_mt[16 * 520];    // 16.25 KB  M^T bf16, padded
    __shared__ float s_cnt[KC];                              // 2 KB
    __shared__ alignas(16) unsigned short s_wh[4][16 * 40];  // 5 KB  per-wave w hi tiles
    __shared__ alignas(16) unsigned short s_wr[4][16 * 40];  // 5 KB  per-wave w residual tiles

    int tid = threadIdx.x;
    for (int i = tid; i < KC * 16; i += 256) {
        float x = cb[i];
        unsigned short h = rne_bf16(x);
        s_cbh[i] = h;
        s_cbr[i] = rne_bf16(x - bf16_to_f32(h));
    }
    for (int i = tid; i < KC * 17; i += 256) {
        int j = i / 17, d = i - j * 17;
        float x = M[i];
        if (d == 16) s_cnt[j] = x;
        else s_mt[d * 520 + j] = rne_bf16(x);
    }
    __syncthreads();

    int lane = tid & 63;
    int col = lane & 15;
    int half8 = ((lane >> 4) & 1) * 8;
    bool hiHalf = lane < 32;
    int wv_id = tid >> 6;
    unsigned short* wlh = &s_wh[wv_id][0];
    unsigned short* wlr = &s_wr[wv_id][0];
    // block covers 4 waves * 4 tiles * 16 tokens = 256 tokens
    int tile0 = (blockIdx.x * 4 + wv_id) * 4;

    for (int t = 0; t < 4; ++t) {
        int tok0 = (tile0 + t) * 16;
        int bh = tok0 >> 12;
        const float* qbase = qkv + (size_t)bh * (48 * 4096) + (tok0 & 4095);

        // A = [qh | qr]
        short8 a8;
        {
            const float* p = qbase + (size_t)half8 * 4096 + col;
#pragma unroll
            for (int i = 0; i < 8; ++i) {
                float x = p[(size_t)i * 4096];
                unsigned short h = rne_bf16(x);
                a8[i] = hiHalf ? (short)h : (short)rne_bf16(x - bf16_to_f32(h));
            }
        }

        floatx4 oacc = {0.f, 0.f, 0.f, 0.f};
        float den[4] = {0.f, 0.f, 0.f, 0.f};

        for (int c = 0; c < 32; ++c) {
            int code = c * 16 + col;
            short8 b1 = *(const short8*)(&s_cbh[code * 16 + half8]);  // [ch|ch]
            short8 b2 = (short8)0;
            if (hiHalf) b2 = *(const short8*)(&s_cbr[code * 16 + half8]);  // [cr|0]
            floatx4 s = {0.f, 0.f, 0.f, 0.f};
            s = __builtin_amdgcn_mfma_f32_16x16x32_bf16(a8, b1, s, 0, 0, 0);
            s = __builtin_amdgcn_mfma_f32_16x16x32_bf16(a8, b2, s, 0, 0, 0);

            float cnt = s_cnt[code];
            int cl = (c & 1) * 16 + col;
#pragma unroll
            for (int r = 0; r < 4; ++r) {
                float wv = __expf(s[r]);
                unsigned short wbh = rne_bf16(wv);
                unsigned short wbr = rne_bf16(wv - bf16_to_f32(wbh));
                den[r] = fmaf(wv, cnt, den[r]);   // exact fp32 w, matches split-w numerator
                int widx = ((lane >> 4) * 4 + r) * 40 + cl;
                wlh[widx] = wbh;
                wlr[widx] = wbr;
            }
            if (c & 1) {
                // PV over the 32 codes just materialized: w = wh + wr (split bf16)
                int aoff = (lane & 15) * 40 + (lane >> 4) * 8;
                short8 wah = *(const short8*)(&wlh[aoff]);
                short8 war = *(const short8*)(&wlr[aoff]);
                short8 mb = *(const short8*)(&s_mt[(lane & 15) * 520 + (c - 1) * 16 + (lane >> 4) * 8]);
                oacc = __builtin_amdgcn_mfma_f32_16x16x32_bf16(wah, mb, oacc, 0, 0, 0);
                oacc = __builtin_amdgcn_mfma_f32_16x16x32_bf16(war, mb, oacc, 0, 0, 0);
            }
        }
        // denominator: sum across the 16 code-columns per row group
#pragma unroll
        for (int m = 1; m < 16; m <<= 1) {
#pragma unroll
            for (int r = 0; r < 4; ++r) den[r] += __shfl_xor(den[r], m, 64);
        }
#pragma unroll
        for (int r = 0; r < 4; ++r) {
            int row = (lane >> 4) * 4 + r;
            float o = oacc[r] / (den[r] + 1e-15f);
            out[(size_t)(tok0 + row) * D16 + col] = o;
        }
    }
}

extern "C" void kernel_launch(void* const* d_in, const int* in_sizes, int n_in,
                              void* d_out, int out_size, void* d_ws, size_t ws_size,
                              hipStream_t stream) {
    const float* qkv = (const float*)d_in[0];   // (8, 384, 64, 64) fp32
    const float* cb  = (const float*)d_in[1];   // (512, 16) fp32
    float* out = (float*)d_out;                 // (8, 128, 64, 64) fp32

    float* M = (float*)d_ws;                                   // K x 17 fp32
    unsigned short* idx = (unsigned short*)((char*)d_ws + 36864);

    hipMemsetAsync(d_ws, 0, KC * 17 * sizeof(float), stream);

    // 256 tokens per block -> NTOK/256 = 1024 blocks
    vq_assign<<<NTOK / 256, 256, 0, stream>>>(qkv, cb, idx);
    vq_segsum<<<256, 256, 0, stream>>>(qkv, idx, M);
    vq_attend<<<NTOK / 256, 256, 0, stream>>>(qkv, cb, M, out);
}

// Round 7
// 256.689 us; speedup vs baseline: 1.3670x; 1.0935x over previous
//
#include <hip/hip_runtime.h>

typedef short short8 __attribute__((ext_vector_type(8)));
typedef float floatx4 __attribute__((ext_vector_type(4)));

#define D16 16
#define KC 512
// tokens: B(8) * heads(8) * HW(4096)
#define NTOK (8 * 8 * 4096)

// workspace layout:
//   [0, 512*17*4)            : M   = K x 17 fp32  (O_tV sums | count)
//   [36864, 36864 + NTOK*2)  : idx = ushort per token

__device__ __forceinline__ unsigned short rne_bf16(float x) {
    unsigned u = __float_as_uint(x);
    return (unsigned short)((u + 0x7fffu + ((u >> 16) & 1u)) >> 16);
}
__device__ __forceinline__ float bf16_to_f32(unsigned short h) {
    return __uint_as_float(((unsigned)h) << 16);
}

// ---------------- kernel 1: nearest-code assignment ----------------
// MFMA split-bf16 scores ([kh|kr] x [ch|ch] + [kh|kr] x [cr|0], 2 MFMA)
// select top-2 candidates per token via packed-float max (code index in the
// low 9 mantissa bits); exact fp32 rescore decides.
extern "C" __global__ __launch_bounds__(256)
void vq_assign(const float* __restrict__ qkv, const float* __restrict__ cb,
               unsigned short* __restrict__ idx)
{
    __shared__ alignas(16) unsigned short s_cbh[KC * 16];  // 16 KB
    __shared__ alignas(16) unsigned short s_cbr[KC * 16];  // 16 KB
    __shared__ float s_cn[KC];                             // 2 KB  |c|^2 (full)
    __shared__ float s_kf[4][16][17];                      // 4.25 KB per-wave fp32 k tiles
    int tid = threadIdx.x;
    for (int i = tid; i < KC * 16; i += 256) {
        float x = cb[i];
        unsigned short h = rne_bf16(x);
        s_cbh[i] = h;
        s_cbr[i] = rne_bf16(x - bf16_to_f32(h));
    }
    for (int j = tid; j < KC; j += 256) {
        float s = 0.f;
#pragma unroll
        for (int d = 0; d < D16; ++d) { float c = cb[j * D16 + d]; s = fmaf(c, c, s); }
        s_cn[j] = s;
    }
    __syncthreads();

    int lane = tid & 63;
    int col = lane & 15;
    int half8 = ((lane >> 4) & 1) * 8;   // k-dim sub-block this lane covers
    bool hiHalf = lane < 32;
    int wv = tid >> 6;
    // block covers 4 waves * 4 tiles * 16 tokens = 256 tokens
    int tile0 = (blockIdx.x * 4 + wv) * 4;

    for (int t = 0; t < 4; ++t) {
        int tok0 = (tile0 + t) * 16;
        int bh = tok0 >> 12;
        const float* kbase = qkv + (size_t)bh * (48 * 4096) + 16 * 4096 + (tok0 & 4095);

        // A = [kh | kr]: lanes 0-31 carry hi(k), lanes 32-63 carry residual(k)
        short8 a8;
        {
            const float* p = kbase + (size_t)half8 * 4096 + col;
#pragma unroll
            for (int i = 0; i < 8; ++i) {
                float x = p[(size_t)i * 4096];
                unsigned short h = rne_bf16(x);
                a8[i] = hiHalf ? (short)h : (short)rne_bf16(x - bf16_to_f32(h));
                if (hiHalf) s_kf[wv][col][half8 + i] = x;  // exact fp32 copy for rescore
            }
        }
        __builtin_amdgcn_wave_barrier();

        // packed top-2 per row: score with code index stuffed in low 9 bits
        float p1[4], p2[4];
#pragma unroll
        for (int r = 0; r < 4; ++r) { p1[r] = -3.4e38f; p2[r] = -3.4e38f; }

        for (int c = 0; c < 32; ++c) {
            int code = c * 16 + col;
            short8 b1 = *(const short8*)(&s_cbh[code * 16 + half8]);  // [ch|ch]
            short8 b2 = (short8)0;
            if (hiHalf) b2 = *(const short8*)(&s_cbr[code * 16 + half8]);  // [cr|0]
            float cn2 = -0.5f * s_cn[code];
            floatx4 acc = { cn2, cn2, cn2, cn2 };
            acc = __builtin_amdgcn_mfma_f32_16x16x32_bf16(a8, b1, acc, 0, 0, 0);
            acc = __builtin_amdgcn_mfma_f32_16x16x32_bf16(a8, b2, acc, 0, 0, 0);
#pragma unroll
            for (int r = 0; r < 4; ++r) {
                unsigned sb = (__float_as_uint(acc[r]) & 0xFFFFFE00u) | (unsigned)code;
                float sp = __uint_as_float(sb);
                float old1 = p1[r];
                p1[r] = fmaxf(old1, sp);
                p2[r] = fmaxf(p2[r], fminf(old1, sp));
            }
        }
        // merge top-2 across the 16 code-columns (lanes sharing a row group)
#pragma unroll
        for (int m = 1; m < 16; m <<= 1) {
#pragma unroll
            for (int r = 0; r < 4; ++r) {
                float o1 = __shfl_xor(p1[r], m, 64);
                float o2 = __shfl_xor(p2[r], m, 64);
                float n1 = fmaxf(p1[r], o1);
                float n2 = fmaxf(fminf(p1[r], o1), fmaxf(p2[r], o2));
                p1[r] = n1; p2[r] = n2;
            }
        }
        // exact fp32 rescore of the 2 candidates; lanes with col<4 own row col
        if (col < 4) {
            int c1 = 0, c2 = 0;
#pragma unroll
            for (int r = 0; r < 4; ++r) {
                if (col == r) {
                    c1 = (int)(__float_as_uint(p1[r]) & 511u);
                    c2 = (int)(__float_as_uint(p2[r]) & 511u);
                }
            }
            int tokrow = (lane >> 4) * 4 + col;
            const float* kf = &s_kf[wv][tokrow][0];
            const float* cb1 = cb + c1 * D16;
            const float* cb2 = cb + c2 * D16;
            float dot1 = 0.f, dot2 = 0.f;
#pragma unroll
            for (int d = 0; d < D16; ++d) {
                float kx = kf[d];
                dot1 = fmaf(kx, cb1[d], dot1);
                dot2 = fmaf(kx, cb2[d], dot2);
            }
            float d1 = fmaf(-2.f, dot1, s_cn[c1]);
            float d2 = fmaf(-2.f, dot2, s_cn[c2]);
            int jw = (d2 < d1 || (d2 == d1 && c2 < c1)) ? c2 : c1;
            idx[tok0 + tokrow] = (unsigned short)jw;
        }
        __builtin_amdgcn_wave_barrier();
    }
}

// ---------------- kernel 2: segment sum of v + counts ----------------
extern "C" __global__ __launch_bounds__(256)
void vq_segsum(const float* __restrict__ qkv, const unsigned short* __restrict__ idx,
               float* __restrict__ M)
{
    __shared__ float s_acc[KC * 17];   // 34.8 KB
    for (int i = threadIdx.x; i < KC * 17; i += 256) s_acc[i] = 0.f;
    __syncthreads();

    for (int n = blockIdx.x * 256 + threadIdx.x; n < NTOK; n += gridDim.x * 256) {
        int bh = n >> 12, hw = n & 4095;
        const float* bv = qkv + (size_t)bh * (48 * 4096) + hw + 32 * 4096;
        int bj = idx[n];
#pragma unroll
        for (int d = 0; d < D16; ++d)
            atomicAdd(&s_acc[bj * 17 + d], bv[d * 4096]);
        atomicAdd(&s_acc[bj * 17 + 16], 1.0f);
    }
    __syncthreads();
    for (int i = threadIdx.x; i < KC * 17; i += 256)
        atomicAdd(&M[i], s_acc[i]);
}

// ---------------- kernel 3: softmax-weighted gather (MFMA, 2-tile ILP) ----------------
// Per c-iter (16 codes), both tiles: QK via [qh|qr]x[ch|ch]+[qr-trick], exp,
// trunc-split w -> swizzled per-(wave,tile) LDS tile laid out as the PV
// A-fragment [wh(16 codes) | wr(16 codes)] along k; PV = ONE MFMA per tile
// with B = [m|m]. Codebook/M B-fragments shared between the two tiles.
extern "C" __global__ __launch_bounds__(256)
void vq_attend(const float* __restrict__ qkv, const float* __restrict__ cb,
               const float* __restrict__ M, float* __restrict__ out)
{
    __shared__ alignas(16) unsigned short s_cbh[KC * 16];      // 16 KB
    __shared__ alignas(16) unsigned short s_cbr[KC * 16];      // 16 KB
    __shared__ alignas(16) unsigned short s_mt[16 * 520];      // 16.25 KB  M^T bf16, padded
    __shared__ float s_cnt[KC];                                // 2 KB
    __shared__ alignas(16) unsigned short s_w[4][2][16 * 40];  // 10 KB  per-(wave,tile) w
    // w tile layout: row = token(0..15), 40 shorts/row; logical cols 0..15 =
    // w_hi(code), 16..31 = w_res(code); physical 8-short block index =
    // logical_block ^ (row>>2)  (conflict-free writes, matches A-frag reads).

    int tid = threadIdx.x;
    for (int i = tid; i < KC * 16; i += 256) {
        float x = cb[i];
        unsigned short h = rne_bf16(x);
        s_cbh[i] = h;
        s_cbr[i] = rne_bf16(x - bf16_to_f32(h));
    }
    for (int i = tid; i < KC * 17; i += 256) {
        int j = i / 17, d = i - j * 17;
        float x = M[i];
        if (d == 16) s_cnt[j] = x;
        else s_mt[d * 520 + j] = rne_bf16(x);
    }
    __syncthreads();

    int lane = tid & 63;
    int col = lane & 15;
    int g = lane >> 4;
    int half8 = (g & 1) * 8;
    bool hiHalf = lane < 32;
    int wv_id = tid >> 6;
    unsigned short* wtA = &s_w[wv_id][0][0];
    unsigned short* wtB = &s_w[wv_id][1][0];
    // block covers 4 waves * 4 tiles * 16 tokens = 256 tokens
    int tile0 = (blockIdx.x * 4 + wv_id) * 4;

    // precomputed w-tile offsets
    int wr_row = g * 4;                               // first row this lane writes
    int w_wr_hi = ((col >> 3) ^ g) << 3;              // phys offset of hi block
    int w_wr_re = (((col >> 3) + 2) ^ g) << 3;        // phys offset of res block
    int w_rd = col * 40 + ((g ^ (col >> 2)) << 3);    // A-frag read: token=col

    for (int tp = 0; tp < 2; ++tp) {
        int tokA = (tile0 + 2 * tp) * 16;
        int tokB = tokA + 16;

        short8 aA, aB;
        {
            const float* p = qkv + (size_t)(tokA >> 12) * (48 * 4096) + (tokA & 4095)
                           + (size_t)half8 * 4096 + col;
#pragma unroll
            for (int i = 0; i < 8; ++i) {
                float x = p[(size_t)i * 4096];
                unsigned short h = rne_bf16(x);
                aA[i] = hiHalf ? (short)h : (short)rne_bf16(x - bf16_to_f32(h));
            }
        }
        {
            const float* p = qkv + (size_t)(tokB >> 12) * (48 * 4096) + (tokB & 4095)
                           + (size_t)half8 * 4096 + col;
#pragma unroll
            for (int i = 0; i < 8; ++i) {
                float x = p[(size_t)i * 4096];
                unsigned short h = rne_bf16(x);
                aB[i] = hiHalf ? (short)h : (short)rne_bf16(x - bf16_to_f32(h));
            }
        }

        floatx4 oA = {0.f, 0.f, 0.f, 0.f}, oB = {0.f, 0.f, 0.f, 0.f};
        float denA[4] = {0.f, 0.f, 0.f, 0.f}, denB[4] = {0.f, 0.f, 0.f, 0.f};

        for (int c = 0; c < 32; ++c) {
            int code = c * 16 + col;
            // shared QK B-fragments
            short8 b1 = *(const short8*)(&s_cbh[code * 16 + half8]);  // [ch|ch]
            short8 b2 = (short8)0;
            if (hiHalf) b2 = *(const short8*)(&s_cbr[code * 16 + half8]);  // [cr|0]

            floatx4 sA = {0.f, 0.f, 0.f, 0.f}, sB = {0.f, 0.f, 0.f, 0.f};
            sA = __builtin_amdgcn_mfma_f32_16x16x32_bf16(aA, b1, sA, 0, 0, 0);
            sB = __builtin_amdgcn_mfma_f32_16x16x32_bf16(aB, b1, sB, 0, 0, 0);
            sA = __builtin_amdgcn_mfma_f32_16x16x32_bf16(aA, b2, sA, 0, 0, 0);
            sB = __builtin_amdgcn_mfma_f32_16x16x32_bf16(aB, b2, sB, 0, 0, 0);

            float cnt = s_cnt[code];
#pragma unroll
            for (int r = 0; r < 4; ++r) {
                int base = (wr_row + r) * 40 + (col & 7);
                // tile A
                float wA = __expf(sA[r]);
                unsigned uA = __float_as_uint(wA);
                float rsA = wA - __uint_as_float(uA & 0xffff0000u);
                denA[r] = fmaf(wA, cnt, denA[r]);
                wtA[base + w_wr_hi] = (unsigned short)(uA >> 16);
                wtA[base + w_wr_re] = (unsigned short)(__float_as_uint(rsA) >> 16);
                // tile B
                float wB = __expf(sB[r]);
                unsigned uB = __float_as_uint(wB);
                float rsB = wB - __uint_as_float(uB & 0xffff0000u);
                denB[r] = fmaf(wB, cnt, denB[r]);
                wtB[base + w_wr_hi] = (unsigned short)(uB >> 16);
                wtB[base + w_wr_re] = (unsigned short)(__float_as_uint(rsB) >> 16);
            }
            // shared PV B-fragment: [m(16 codes) | m(16 codes)]
            short8 mb = *(const short8*)(&s_mt[col * 520 + c * 16 + half8]);
            short8 wfA = *(const short8*)(&wtA[w_rd]);
            short8 wfB = *(const short8*)(&wtB[w_rd]);
            oA = __builtin_amdgcn_mfma_f32_16x16x32_bf16(wfA, mb, oA, 0, 0, 0);
            oB = __builtin_amdgcn_mfma_f32_16x16x32_bf16(wfB, mb, oB, 0, 0, 0);
        }
        // denominator: sum across the 16 code-columns per row group
#pragma unroll
        for (int m = 1; m < 16; m <<= 1) {
#pragma unroll
            for (int r = 0; r < 4; ++r) {
                denA[r] += __shfl_xor(denA[r], m, 64);
                denB[r] += __shfl_xor(denB[r], m, 64);
            }
        }
#pragma unroll
        for (int r = 0; r < 4; ++r) {
            int row = g * 4 + r;
            out[(size_t)(tokA + row) * D16 + col] = oA[r] / (denA[r] + 1e-15f);
            out[(size_t)(tokB + row) * D16 + col] = oB[r] / (denB[r] + 1e-15f);
        }
    }
}

extern "C" void kernel_launch(void* const* d_in, const int* in_sizes, int n_in,
                              void* d_out, int out_size, void* d_ws, size_t ws_size,
                              hipStream_t stream) {
    const float* qkv = (const float*)d_in[0];   // (8, 384, 64, 64) fp32
    const float* cb  = (const float*)d_in[1];   // (512, 16) fp32
    float* out = (float*)d_out;                 // (8, 128, 64, 64) fp32

    float* M = (float*)d_ws;                                   // K x 17 fp32
    unsigned short* idx = (unsigned short*)((char*)d_ws + 36864);

    hipMemsetAsync(d_ws, 0, KC * 17 * sizeof(float), stream);

    // 256 tokens per block -> NTOK/256 = 1024 blocks
    vq_assign<<<NTOK / 256, 256, 0, stream>>>(qkv, cb, idx);
    vq_segsum<<<256, 256, 0, stream>>>(qkv, idx, M);
    vq_attend<<<NTOK / 256, 256, 0, stream>>>(qkv, cb, M, out);
}

// Round 9
// 255.299 us; speedup vs baseline: 1.3745x; 1.0054x over previous
//
#include <hip/hip_runtime.h>

typedef short short8 __attribute__((ext_vector_type(8)));
typedef float floatx4 __attribute__((ext_vector_type(4)));

#define D16 16
#define KC 512
// tokens: B(8) * heads(8) * HW(4096)
#define NTOK (8 * 8 * 4096)

// workspace layout:
//   [0, 512*17*4)            : M   = K x 17 fp32  (O_tV sums | count)
//   [36864, 36864 + NTOK*2)  : idx = ushort per token

__device__ __forceinline__ unsigned short rne_bf16(float x) {
    unsigned u = __float_as_uint(x);
    return (unsigned short)((u + 0x7fffu + ((u >> 16) & 1u)) >> 16);
}
__device__ __forceinline__ float bf16_to_f32(unsigned short h) {
    return __uint_as_float(((unsigned)h) << 16);
}

// ---------------- kernel 1: nearest-code assignment ----------------
// MFMA split-bf16 scores ([kh|kr] x [ch|ch] + [kh|kr] x [cr|0], 2 MFMA)
// select top-2 candidates per token via packed-float max (code index in the
// low 9 mantissa bits); exact fp32 rescore decides. Full split precision kept
// here: argmin flips were the round-3 2e-2 failure mode.
extern "C" __global__ __launch_bounds__(256)
void vq_assign(const float* __restrict__ qkv, const float* __restrict__ cb,
               unsigned short* __restrict__ idx)
{
    __shared__ alignas(16) unsigned short s_cbh[KC * 16];  // 16 KB
    __shared__ alignas(16) unsigned short s_cbr[KC * 16];  // 16 KB
    __shared__ float s_cn[KC];                             // 2 KB  |c|^2 (full)
    __shared__ float s_kf[4][16][17];                      // 4.25 KB per-wave fp32 k tiles
    int tid = threadIdx.x;
    for (int i = tid; i < KC * 16; i += 256) {
        float x = cb[i];
        unsigned short h = rne_bf16(x);
        s_cbh[i] = h;
        s_cbr[i] = rne_bf16(x - bf16_to_f32(h));
    }
    for (int j = tid; j < KC; j += 256) {
        float s = 0.f;
#pragma unroll
        for (int d = 0; d < D16; ++d) { float c = cb[j * D16 + d]; s = fmaf(c, c, s); }
        s_cn[j] = s;
    }
    __syncthreads();

    int lane = tid & 63;
    int col = lane & 15;
    int half8 = ((lane >> 4) & 1) * 8;   // k-dim sub-block this lane covers
    bool hiHalf = lane < 32;
    int wv = tid >> 6;
    // block covers 4 waves * 4 tiles * 16 tokens = 256 tokens
    int tile0 = (blockIdx.x * 4 + wv) * 4;

    for (int t = 0; t < 4; ++t) {
        int tok0 = (tile0 + t) * 16;
        int bh = tok0 >> 12;
        const float* kbase = qkv + (size_t)bh * (48 * 4096) + 16 * 4096 + (tok0 & 4095);

        // A = [kh | kr]: lanes 0-31 carry hi(k), lanes 32-63 carry residual(k)
        short8 a8;
        {
            const float* p = kbase + (size_t)half8 * 4096 + col;
#pragma unroll
            for (int i = 0; i < 8; ++i) {
                float x = p[(size_t)i * 4096];
                unsigned short h = rne_bf16(x);
                a8[i] = hiHalf ? (short)h : (short)rne_bf16(x - bf16_to_f32(h));
                if (hiHalf) s_kf[wv][col][half8 + i] = x;  // exact fp32 copy for rescore
            }
        }
        __builtin_amdgcn_wave_barrier();

        // packed top-2 per row: score with code index stuffed in low 9 bits
        float p1[4], p2[4];
#pragma unroll
        for (int r = 0; r < 4; ++r) { p1[r] = -3.4e38f; p2[r] = -3.4e38f; }

        for (int c = 0; c < 32; ++c) {
            int code = c * 16 + col;
            short8 b1 = *(const short8*)(&s_cbh[code * 16 + half8]);  // [ch|ch]
            short8 b2 = (short8)0;
            if (hiHalf) b2 = *(const short8*)(&s_cbr[code * 16 + half8]);  // [cr|0]
            float cn2 = -0.5f * s_cn[code];
            floatx4 acc = { cn2, cn2, cn2, cn2 };
            acc = __builtin_amdgcn_mfma_f32_16x16x32_bf16(a8, b1, acc, 0, 0, 0);
            acc = __builtin_amdgcn_mfma_f32_16x16x32_bf16(a8, b2, acc, 0, 0, 0);
#pragma unroll
            for (int r = 0; r < 4; ++r) {
                unsigned sb = (__float_as_uint(acc[r]) & 0xFFFFFE00u) | (unsigned)code;
                float sp = __uint_as_float(sb);
                float old1 = p1[r];
                p1[r] = fmaxf(old1, sp);
                p2[r] = fmaxf(p2[r], fminf(old1, sp));
            }
        }
        // merge top-2 across the 16 code-columns (lanes sharing a row group)
#pragma unroll
        for (int m = 1; m < 16; m <<= 1) {
#pragma unroll
            for (int r = 0; r < 4; ++r) {
                float o1 = __shfl_xor(p1[r], m, 64);
                float o2 = __shfl_xor(p2[r], m, 64);
                float n1 = fmaxf(p1[r], o1);
                float n2 = fmaxf(fminf(p1[r], o1), fmaxf(p2[r], o2));
                p1[r] = n1; p2[r] = n2;
            }
        }
        // exact fp32 rescore of the 2 candidates; lanes with col<4 own row col
        if (col < 4) {
            int c1 = 0, c2 = 0;
#pragma unroll
            for (int r = 0; r < 4; ++r) {
                if (col == r) {
                    c1 = (int)(__float_as_uint(p1[r]) & 511u);
                    c2 = (int)(__float_as_uint(p2[r]) & 511u);
                }
            }
            int tokrow = (lane >> 4) * 4 + col;
            const float* kf = &s_kf[wv][tokrow][0];
            const float* cb1 = cb + c1 * D16;
            const float* cb2 = cb + c2 * D16;
            float dot1 = 0.f, dot2 = 0.f;
#pragma unroll
            for (int d = 0; d < D16; ++d) {
                float kx = kf[d];
                dot1 = fmaf(kx, cb1[d], dot1);
                dot2 = fmaf(kx, cb2[d], dot2);
            }
            float d1 = fmaf(-2.f, dot1, s_cn[c1]);
            float d2 = fmaf(-2.f, dot2, s_cn[c2]);
            int jw = (d2 < d1 || (d2 == d1 && c2 < c1)) ? c2 : c1;
            idx[tok0 + tokrow] = (unsigned short)jw;
        }
        __builtin_amdgcn_wave_barrier();
    }
}

// ---------------- kernel 2: segment sum of v + counts ----------------
extern "C" __global__ __launch_bounds__(256)
void vq_segsum(const float* __restrict__ qkv, const unsigned short* __restrict__ idx,
               float* __restrict__ M)
{
    __shared__ float s_acc[KC * 17];   // 34.8 KB
    for (int i = threadIdx.x; i < KC * 17; i += 256) s_acc[i] = 0.f;
    __syncthreads();

    for (int n = blockIdx.x * 256 + threadIdx.x; n < NTOK; n += gridDim.x * 256) {
        int bh = n >> 12, hw = n & 4095;
        const float* bv = qkv + (size_t)bh * (48 * 4096) + hw + 32 * 4096;
        int bj = idx[n];
#pragma unroll
        for (int d = 0; d < D16; ++d)
            atomicAdd(&s_acc[bj * 17 + d], bv[d * 4096]);
        atomicAdd(&s_acc[bj * 17 + 16], 1.0f);
    }
    __syncthreads();
    for (int i = threadIdx.x; i < KC * 17; i += 256)
        atomicAdd(&M[i], s_acc[i]);
}

// ---------------- kernel 3: softmax-weighted gather (MFMA, lean) ----------------
// Numerics: S~ = q . bf16(c)  (q exact via [qh|qr] x [ch|ch], 1 MFMA);
// w~ = trunc-bf16(exp(S~)) used in BOTH numerator (PV MFMA) and denominator
// (fp32 fma) -> per-code common-mode rounding cancels in the ratio.
// PV: one MFMA per 32 codes per tile, A = w~[16 tok][32 codes] from a
// per-(wave,tile) XOR-swizzled LDS tile, B = M^T fragment (shared by tiles).
// LDS 44.25 KB -> 3 blocks/CU.
extern "C" __global__ __launch_bounds__(256)
void vq_attend(const float* __restrict__ qkv, const float* __restrict__ cb,
               const float* __restrict__ M, float* __restrict__ out)
{
    __shared__ alignas(16) unsigned short s_cbh[KC * 16];      // 16 KB
    __shared__ alignas(16) unsigned short s_mt[16 * 520];      // 16.25 KB  M^T bf16, padded
    __shared__ float s_cnt[KC];                                // 2 KB
    __shared__ alignas(16) unsigned short s_w[4][2][16 * 40];  // 10 KB  per-(wave,tile) w
    // w tile: row = token(0..15), 40 shorts/row; logical cols 0..31 = codes of
    // the current 32-code group; physical 8-short block = (col>>3) ^ (row>>2).

    int tid = threadIdx.x;
    for (int i = tid; i < KC * 16; i += 256) s_cbh[i] = rne_bf16(cb[i]);
    for (int i = tid; i < KC * 17; i += 256) {
        int j = i / 17, d = i - j * 17;
        float x = M[i];
        if (d == 16) s_cnt[j] = x;
        else s_mt[d * 520 + j] = rne_bf16(x);
    }
    __syncthreads();

    int lane = tid & 63;
    int col = lane & 15;
    int g = lane >> 4;
    int half8 = (g & 1) * 8;
    bool hiHalf = lane < 32;
    int wv_id = tid >> 6;
    unsigned short* wtA = &s_w[wv_id][0][0];
    unsigned short* wtB = &s_w[wv_id][1][0];
    // block covers 4 waves * 4 tiles * 16 tokens = 256 tokens
    int tile0 = (blockIdx.x * 4 + wv_id) * 4;

    // w-tile offsets (write: this lane produces tokens g*4+r, code cg*16+col)
    int wr_row = g * 4;
    int wsel0 = (((col >> 3) + 0) ^ g) * 8 + (col & 7);  // cg=0 block
    int wsel1 = (((col >> 3) + 2) ^ g) * 8 + (col & 7);  // cg=1 block
    int w_rd = col * 40 + ((g ^ (col >> 2)) << 3);       // PV A-frag: token=col, kblk=g

    for (int tp = 0; tp < 2; ++tp) {
        int tokA = (tile0 + 2 * tp) * 16;
        int tokB = tokA + 16;

        short8 aA, aB;   // QK A-frags: [qh | qr] (exact q, split halves)
        {
            const float* p = qkv + (size_t)(tokA >> 12) * (48 * 4096) + (tokA & 4095)
                           + (size_t)half8 * 4096 + col;
#pragma unroll
            for (int i = 0; i < 8; ++i) {
                float x = p[(size_t)i * 4096];
                unsigned short h = rne_bf16(x);
                aA[i] = hiHalf ? (short)h : (short)rne_bf16(x - bf16_to_f32(h));
            }
        }
        {
            const float* p = qkv + (size_t)(tokB >> 12) * (48 * 4096) + (tokB & 4095)
                           + (size_t)half8 * 4096 + col;
#pragma unroll
            for (int i = 0; i < 8; ++i) {
                float x = p[(size_t)i * 4096];
                unsigned short h = rne_bf16(x);
                aB[i] = hiHalf ? (short)h : (short)rne_bf16(x - bf16_to_f32(h));
            }
        }

        floatx4 oA = {0.f, 0.f, 0.f, 0.f}, oB = {0.f, 0.f, 0.f, 0.f};
        float denA[4] = {0.f, 0.f, 0.f, 0.f}, denB[4] = {0.f, 0.f, 0.f, 0.f};

        for (int c32 = 0; c32 < 16; ++c32) {
#pragma unroll
            for (int cg = 0; cg < 2; ++cg) {
                int code = (c32 * 2 + cg) * 16 + col;
                short8 b1 = *(const short8*)(&s_cbh[code * 16 + half8]);  // [ch|ch]
                floatx4 sA = {0.f, 0.f, 0.f, 0.f}, sB = {0.f, 0.f, 0.f, 0.f};
                sA = __builtin_amdgcn_mfma_f32_16x16x32_bf16(aA, b1, sA, 0, 0, 0);
                sB = __builtin_amdgcn_mfma_f32_16x16x32_bf16(aB, b1, sB, 0, 0, 0);
                float cnt = s_cnt[code];
                int wsel = cg ? wsel1 : wsel0;
#pragma unroll
                for (int r = 0; r < 4; ++r) {
                    int base = (wr_row + r) * 40 + wsel;
                    float wA = __expf(sA[r]);
                    unsigned uA = __float_as_uint(wA) & 0xffff0000u;
                    denA[r] = fmaf(__uint_as_float(uA), cnt, denA[r]);
                    wtA[base] = (unsigned short)(uA >> 16);
                    float wB = __expf(sB[r]);
                    unsigned uB = __float_as_uint(wB) & 0xffff0000u;
                    denB[r] = fmaf(__uint_as_float(uB), cnt, denB[r]);
                    wtB[base] = (unsigned short)(uB >> 16);
                }
            }
            // PV over the 32 codes just materialized (B shared by both tiles)
            short8 mb  = *(const short8*)(&s_mt[col * 520 + c32 * 32 + g * 8]);
            short8 wfA = *(const short8*)(&wtA[w_rd]);
            short8 wfB = *(const short8*)(&wtB[w_rd]);
            oA = __builtin_amdgcn_mfma_f32_16x16x32_bf16(wfA, mb, oA, 0, 0, 0);
            oB = __builtin_amdgcn_mfma_f32_16x16x32_bf16(wfB, mb, oB, 0, 0, 0);
        }
        // denominator: sum across the 16 code-columns per row group
#pragma unroll
        for (int m = 1; m < 16; m <<= 1) {
#pragma unroll
            for (int r = 0; r < 4; ++r) {
                denA[r] += __shfl_xor(denA[r], m, 64);
                denB[r] += __shfl_xor(denB[r], m, 64);
            }
        }
#pragma unroll
        for (int r = 0; r < 4; ++r) {
            int row = g * 4 + r;
            out[(size_t)(tokA + row) * D16 + col] = oA[r] / (denA[r] + 1e-15f);
            out[(size_t)(tokB + row) * D16 + col] = oB[r] / (denB[r] + 1e-15f);
        }
    }
}

extern "C" void kernel_launch(void* const* d_in, const int* in_sizes, int n_in,
                              void* d_out, int out_size, void* d_ws, size_t ws_size,
                              hipStream_t stream) {
    const float* qkv = (const float*)d_in[0];   // (8, 384, 64, 64) fp32
    const float* cb  = (const float*)d_in[1];   // (512, 16) fp32
    float* out = (float*)d_out;                 // (8, 128, 64, 64) fp32

    float* M = (float*)d_ws;                                   // K x 17 fp32
    unsigned short* idx = (unsigned short*)((char*)d_ws + 36864);

    hipMemsetAsync(d_ws, 0, KC * 17 * sizeof(float), stream);

    vq_assign<<<NTOK / 256, 256, 0, stream>>>(qkv, cb, idx);
    vq_segsum<<<1024, 256, 0, stream>>>(qkv, idx, M);
    vq_attend<<<NTOK / 256, 256, 0, stream>>>(qkv, cb, M, out);
}